// Round 5
// baseline (36.253 us; speedup 1.0000x reference)
//
#include <hip/hip_runtime.h>

typedef __attribute__((ext_vector_type(4))) float f32x4;

constexpr int Bdim = 8192;   // rows of x
constexpr int Cdim = 4096;   // rows of W (= output cols)
constexpr int Ddim = 256;    // K

// 15*exp(-t) == +0.0f in f32 (incl. denormal range) for t >= ~106.7; margin -> 112.
constexpr float ZERO_THRESH = 112.0f;

// ---------------------------------------------------------------------------
// Kernel 1: per-block partial max of ||W_c||^2. One wave per W row, 4 rows
// per block, 1024 blocks -> pmax[1024]. Reads 4 MB, writes 4 KB.
// ---------------------------------------------------------------------------
__global__ __launch_bounds__(256) void wmax_kernel(const float* __restrict__ W,
                                                   float* __restrict__ pmax) {
  __shared__ float sm[4];
  int tid  = threadIdx.x;
  int lane = tid & 63;
  int wid  = tid >> 6;
  int row  = blockIdx.x * 4 + wid;
  f32x4 v = *(const f32x4*)(W + (size_t)row * Ddim + lane * 4);
  float s = v[0]*v[0] + v[1]*v[1] + v[2]*v[2] + v[3]*v[3];
  #pragma unroll
  for (int off = 32; off > 0; off >>= 1) s += __shfl_xor(s, off, 64);
  if (lane == 0) sm[wid] = s;
  __syncthreads();
  if (tid == 0) pmax[blockIdx.x] = fmaxf(fmaxf(sm[0], sm[1]), fmaxf(sm[2], sm[3]));
}

// ---------------------------------------------------------------------------
// Kernel 2: one block per 4-row output slab (4 x 4096 f32 = 64 KB contiguous).
// Screen (Cauchy-Schwarz): ||x_b - w_c||^2 >= (||x_b|| - max||W||)^2. If the
// bound > 112 for all 4 slab rows, every slab output is exactly +0.0f in f32
// -> linear nontemporal zero fill at the write roofline. Otherwise: exact
// f32 direct computation (block-uniform branch; not taken for bench input).
// The 4 x-rows are loaded once (4 KB, coalesced): they feed BOTH the screen's
// row norms and the slow path's LDS staging.
// ---------------------------------------------------------------------------
__global__ __launch_bounds__(256) void rbf_rows(const float* __restrict__ x,
                                                const float* __restrict__ W,
                                                const float* __restrict__ pmax,
                                                float* __restrict__ out) {
  __shared__ float xl[4][Ddim];   // 4 KB: staged x rows (wave w = row w)
  __shared__ float xn[4];         // per-row ||x||^2
  __shared__ float wm4[4];        // per-wave partial of max||W||^2

  int tid  = threadIdx.x;
  int lane = tid & 63;
  int wid  = tid >> 6;
  int row0 = blockIdx.x * 4;

  // one coalesced 16B load per thread: 4 rows x 256 f32
  f32x4 v = *(const f32x4*)(x + (size_t)row0 * Ddim + tid * 4);
  *(f32x4*)&xl[wid][lane * 4] = v;
  float s = v[0]*v[0] + v[1]*v[1] + v[2]*v[2] + v[3]*v[3];
  #pragma unroll
  for (int off = 32; off > 0; off >>= 1) s += __shfl_xor(s, off, 64);

  // independent in parallel: block-wide max over the 1024 W partial maxes
  float wmx = fmaxf(fmaxf(pmax[tid], pmax[tid + 256]),
                    fmaxf(pmax[tid + 512], pmax[tid + 768]));
  #pragma unroll
  for (int off = 32; off > 0; off >>= 1) wmx = fmaxf(wmx, __shfl_xor(wmx, off, 64));

  if (lane == 0) { xn[wid] = s; wm4[wid] = wmx; }
  __syncthreads();
  float xmin  = fminf(fminf(xn[0], xn[1]), fminf(xn[2], xn[3]));
  float wmax2 = fmaxf(fmaxf(wm4[0], wm4[1]), fmaxf(wm4[2], wm4[3]));

  float gap = sqrtf(xmin) - sqrtf(wmax2);
  if (gap > 0.0f && gap * gap > ZERO_THRESH) {
    // ---- fast path: 64 KB contiguous nontemporal zero fill ----
    f32x4 z = {0.0f, 0.0f, 0.0f, 0.0f};
    float* base = out + (size_t)row0 * Cdim + tid * 4;
    #pragma unroll
    for (int p = 0; p < 16; ++p)
      __builtin_nontemporal_store(z, (f32x4*)(base + (size_t)p * 1024));
    return;
  }

  // ---- slow path: exact f32 metric for the slab (xl already staged) ----
  for (int ch = 0; ch < Cdim / 256; ++ch) {
    int col = ch * 256 + tid;
    const float* wrow = W + (size_t)col * Ddim;
    float m0 = 0.f, m1 = 0.f, m2 = 0.f, m3 = 0.f;
    for (int d = 0; d < Ddim; d += 4) {
      f32x4 wv = *(const f32x4*)(wrow + d);
      #pragma unroll
      for (int e = 0; e < 4; ++e) {
        float w  = wv[e];
        float d0 = w - xl[0][d + e]; m0 += d0 * d0;
        float d1 = w - xl[1][d + e]; m1 += d1 * d1;
        float d2 = w - xl[2][d + e]; m2 += d2 * d2;
        float d3 = w - xl[3][d + e]; m3 += d3 * d3;
      }
    }
    out[(size_t)(row0 + 0) * Cdim + col] = 15.0f * expf(-m0);
    out[(size_t)(row0 + 1) * Cdim + col] = 15.0f * expf(-m1);
    out[(size_t)(row0 + 2) * Cdim + col] = 15.0f * expf(-m2);
    out[(size_t)(row0 + 3) * Cdim + col] = 15.0f * expf(-m3);
  }
}

extern "C" void kernel_launch(void* const* d_in, const int* in_sizes, int n_in,
                              void* d_out, int out_size, void* d_ws, size_t ws_size,
                              hipStream_t stream) {
  const float* x = (const float*)d_in[0];   // [8192, 256] f32
  const float* W = (const float*)d_in[1];   // [4096, 256] f32
  float* out     = (float*)d_out;           // [8192, 4096] f32
  float* pmax    = (float*)d_ws;            // 1024 f32 = 4 KB scratch

  // 1) W-norm partial maxes: 4096 rows / 4 per block
  wmax_kernel<<<Cdim / 4, 256, 0, stream>>>(W, pmax);

  // 2) screened slab kernel: 2048 blocks x 4 contiguous output rows
  rbf_rows<<<Bdim / 4, 256, 0, stream>>>(x, W, pmax, out);
}

// Round 6
// 28.241 us; speedup vs baseline: 1.2837x; 1.2837x over previous
//
#include <hip/hip_runtime.h>

typedef __attribute__((ext_vector_type(4))) float f32x4;

constexpr int Bdim = 8192;   // rows of x
constexpr int Cdim = 4096;   // rows of W (= output cols)
constexpr int Ddim = 256;    // K

// 15*exp(-t) == +0.0f in f32 (incl. denormal range) for t >= ~106.7; margin -> 112.
constexpr float ZERO_THRESH = 112.0f;

// ---------------------------------------------------------------------------
// Kernel 1: per-block partial max of ||W_c||^2. One wave per W row, 4 rows
// per block, 1024 blocks -> pmax[1024]. Reads 4 MB, writes 4 KB.
// ---------------------------------------------------------------------------
__global__ __launch_bounds__(256) void wmax_kernel(const float* __restrict__ W,
                                                   float* __restrict__ pmax) {
  __shared__ float sm[4];
  int tid  = threadIdx.x;
  int lane = tid & 63;
  int wid  = tid >> 6;
  int row  = blockIdx.x * 4 + wid;
  f32x4 v = *(const f32x4*)(W + (size_t)row * Ddim + lane * 4);
  float s = v[0]*v[0] + v[1]*v[1] + v[2]*v[2] + v[3]*v[3];
  #pragma unroll
  for (int off = 32; off > 0; off >>= 1) s += __shfl_xor(s, off, 64);
  if (lane == 0) sm[wid] = s;
  __syncthreads();
  if (tid == 0) pmax[blockIdx.x] = fmaxf(fmaxf(sm[0], sm[1]), fmaxf(sm[2], sm[3]));
}

// ---------------------------------------------------------------------------
// Kernel 2: one block per 4-row output slab (4 x 4096 f32 = 64 KB contiguous).
// Screen (Cauchy-Schwarz): ||x_b - w_c||^2 >= (||x_b|| - max||W||)^2. If the
// bound > 112 for all 4 slab rows, every slab output is exactly +0.0f in f32
// -> linear zero fill at the write roofline (regular stores: L2 write-combine
// is the fast path on gfx950; nontemporal stores measured -25% in R5).
// Otherwise: exact f32 direct computation (block-uniform branch; not taken
// for the bench input). The 4 x-rows are loaded once (coalesced 4 KB) and
// feed BOTH the screen's row norms and the slow path's LDS staging.
// ---------------------------------------------------------------------------
__global__ __launch_bounds__(256) void rbf_rows(const float* __restrict__ x,
                                                const float* __restrict__ W,
                                                const float* __restrict__ pmax,
                                                float* __restrict__ out) {
  __shared__ float xl[4][Ddim];   // 4 KB: staged x rows (wave w = row w)
  __shared__ float xn[4];         // per-row ||x||^2
  __shared__ float wm4[4];        // per-wave partial of max||W||^2

  int tid  = threadIdx.x;
  int lane = tid & 63;
  int wid  = tid >> 6;
  int row0 = blockIdx.x * 4;

  // one coalesced 16B load per thread: 4 rows x 256 f32
  f32x4 v = *(const f32x4*)(x + (size_t)row0 * Ddim + tid * 4);
  *(f32x4*)&xl[wid][lane * 4] = v;
  float s = v[0]*v[0] + v[1]*v[1] + v[2]*v[2] + v[3]*v[3];
  #pragma unroll
  for (int off = 32; off > 0; off >>= 1) s += __shfl_xor(s, off, 64);

  // independent in parallel: block-wide max over the 1024 W partial maxes
  float wmx = fmaxf(fmaxf(pmax[tid], pmax[tid + 256]),
                    fmaxf(pmax[tid + 512], pmax[tid + 768]));
  #pragma unroll
  for (int off = 32; off > 0; off >>= 1) wmx = fmaxf(wmx, __shfl_xor(wmx, off, 64));

  if (lane == 0) { xn[wid] = s; wm4[wid] = wmx; }
  __syncthreads();
  float xmin  = fminf(fminf(xn[0], xn[1]), fminf(xn[2], xn[3]));
  float wmax2 = fmaxf(fmaxf(wm4[0], wm4[1]), fmaxf(wm4[2], wm4[3]));

  float gap = sqrtf(xmin) - sqrtf(wmax2);
  if (gap > 0.0f && gap * gap > ZERO_THRESH) {
    // ---- fast path: 64 KB contiguous zero fill, regular f32x4 stores ----
    f32x4 z = {0.0f, 0.0f, 0.0f, 0.0f};
    float* base = out + (size_t)row0 * Cdim + tid * 4;
    #pragma unroll
    for (int p = 0; p < 16; ++p)
      *(f32x4*)(base + (size_t)p * 1024) = z;
    return;
  }

  // ---- slow path: exact f32 metric for the slab (xl already staged) ----
  for (int ch = 0; ch < Cdim / 256; ++ch) {
    int col = ch * 256 + tid;
    const float* wrow = W + (size_t)col * Ddim;
    float m0 = 0.f, m1 = 0.f, m2 = 0.f, m3 = 0.f;
    for (int d = 0; d < Ddim; d += 4) {
      f32x4 wv = *(const f32x4*)(wrow + d);
      #pragma unroll
      for (int e = 0; e < 4; ++e) {
        float w  = wv[e];
        float d0 = w - xl[0][d + e]; m0 += d0 * d0;
        float d1 = w - xl[1][d + e]; m1 += d1 * d1;
        float d2 = w - xl[2][d + e]; m2 += d2 * d2;
        float d3 = w - xl[3][d + e]; m3 += d3 * d3;
      }
    }
    out[(size_t)(row0 + 0) * Cdim + col] = 15.0f * expf(-m0);
    out[(size_t)(row0 + 1) * Cdim + col] = 15.0f * expf(-m1);
    out[(size_t)(row0 + 2) * Cdim + col] = 15.0f * expf(-m2);
    out[(size_t)(row0 + 3) * Cdim + col] = 15.0f * expf(-m3);
  }
}

extern "C" void kernel_launch(void* const* d_in, const int* in_sizes, int n_in,
                              void* d_out, int out_size, void* d_ws, size_t ws_size,
                              hipStream_t stream) {
  const float* x = (const float*)d_in[0];   // [8192, 256] f32
  const float* W = (const float*)d_in[1];   // [4096, 256] f32
  float* out     = (float*)d_out;           // [8192, 4096] f32
  float* pmax    = (float*)d_ws;            // 1024 f32 = 4 KB scratch

  // 1) W-norm partial maxes: 4096 rows / 4 per block
  wmax_kernel<<<Cdim / 4, 256, 0, stream>>>(W, pmax);

  // 2) screened slab kernel: 2048 blocks x 4 contiguous output rows
  rbf_rows<<<Bdim / 4, 256, 0, stream>>>(x, W, pmax, out);
}